// Round 24
// baseline (299.964 us; speedup 1.0000x reference)
//
#include <hip/hip_runtime.h>
#include <hip/hip_bf16.h>

typedef __attribute__((ext_vector_type(8))) short bf16x8;
typedef __attribute__((ext_vector_type(4))) float f32x4;
typedef __attribute__((ext_vector_type(16))) float f32x16;

#define DEVI __device__ __forceinline__

DEVI unsigned short f2bf(float f) {
  union { float f; unsigned u; } v; v.f = f;
  unsigned r = v.u + 0x7FFFu + ((v.u >> 16) & 1u);
  return (unsigned short)(r >> 16);
}

DEVI unsigned cvtpk(float lo, float hi) {
  unsigned r;
  asm("v_cvt_pk_bf16_f32 %0, %1, %2" : "=v"(r) : "v"(lo), "v"(hi));
  return r;
}

DEVI void gload16(const void* g, void* l) {
  __builtin_amdgcn_global_load_lds(
      (const __attribute__((address_space(1))) unsigned int*)g,
      (__attribute__((address_space(3))) unsigned int*)l, 16, 0, 0);
}

// -------- merged prep: bid<2048 -> x fp32->bf16 ; else 13 transpose slices --------
__global__ void k_prep(const float* __restrict__ x, unsigned short* __restrict__ xb,
                       const float* __restrict__ Wq, const float* __restrict__ Wk,
                       const float* __restrict__ Wv, const float* __restrict__ Wo,
                       unsigned short* __restrict__ Wt, unsigned short* __restrict__ Wot) {
  __shared__ float t[32][33];
  int bid = blockIdx.x;
  if (bid < 2048) {
    int i = bid * 256 + threadIdx.x;
    const int stride = 2048 * 256;
#pragma unroll
    for (int it = 0; it < 8; ++it, i += stride) {
      float4 v = ((const float4*)x)[i];
      ushort4 o;
      o.x = f2bf(v.x); o.y = f2bf(v.y); o.z = f2bf(v.z); o.w = f2bf(v.w);
      ((ushort4*)xb)[i] = o;
    }
  } else {
    int b2 = bid - 2048;
    int z = b2 >> 8, rem = b2 & 255;
    int r0 = (rem >> 3) * 32, c0 = (rem & 7) * 32;
    const float* in = z < 4 ? Wq : (z < 8 ? Wk : (z < 12 ? Wv : Wo));
    size_t ibase = (size_t)(z < 12 ? (z & 3) : 0) * 262144;
    unsigned short* out = z < 12 ? (Wt + (size_t)z * 262144) : Wot;
    int tx = threadIdx.x & 31, ty = threadIdx.x >> 5;
    for (int i = 0; i < 32; i += 8)
      t[ty + i][tx] = in[ibase + (size_t)(r0 + ty + i) * 256 + (c0 + tx)];
    __syncthreads();
    for (int i = 0; i < 32; i += 8)
      out[(size_t)(c0 + ty + i) * 1024 + (r0 + tx)] = f2bf(t[tx][ty + i]);
  }
}

// ---------------- fused QKV GEMM: [16384,1024] x [3072,1024]^T, 128x128 tiles ----------------
__global__ __launch_bounds__(256, 3) void k_gemmqkv(
    const unsigned short* __restrict__ A,
    const unsigned short* __restrict__ B,
    const float* __restrict__ bq, const float* __restrict__ bk,
    const float* __restrict__ bv,
    unsigned short* __restrict__ Qb, unsigned short* __restrict__ Kg,
    unsigned short* __restrict__ Vt, float qscale)
{
  __shared__ unsigned short As[128 * 64];
  __shared__ unsigned short Bs[128 * 64];
  int tid = threadIdx.x;
  int w = tid >> 6, l = tid & 63;
  int lg = l >> 4, lm = l & 15;
  int wr = w >> 1, wc = w & 1;
  int bid = blockIdx.x;
  int wg = (bid & 7) * 384 + (bid >> 3);
  int rowblk = wg / 24, colblk = wg % 24;
  int row0 = rowblk * 128, col0 = colblk * 128;

  const f32x4 fz = {0.f, 0.f, 0.f, 0.f};
  f32x4 acc[4][4];
  for (int i = 0; i < 4; i++) for (int j = 0; j < 4; j++) acc[i][j] = fz;

  for (int t = 0; t < 16; ++t) {
    int k0 = t << 6;
    __syncthreads();
#pragma unroll
    for (int j = 0; j < 4; ++j) {
      int ch = j * 256 + tid;
      int row = ch >> 3, cirp = (ch & 7) ^ (row & 7);
      gload16(A + (size_t)(row0 + row) * 1024 + k0 + cirp * 8,
              As + (size_t)(j * 256 + w * 64) * 8);
      gload16(B + (size_t)(col0 + row) * 1024 + k0 + cirp * 8,
              Bs + (size_t)(j * 256 + w * 64) * 8);
    }
    __syncthreads();
#pragma unroll
    for (int kt = 0; kt < 2; ++kt) {
      bf16x8 bfr[4];
#pragma unroll
      for (int ni = 0; ni < 4; ++ni) {
        int r = wc * 64 + ni * 16 + lm;
        bfr[ni] = *(const bf16x8*)((const char*)Bs + r * 128 + ((kt * 64 + lg * 16) ^ ((r & 7) << 4)));
      }
#pragma unroll
      for (int mi = 0; mi < 4; ++mi) {
        int r = wr * 64 + mi * 16 + lm;
        bf16x8 afr = *(const bf16x8*)((const char*)As + r * 128 + ((kt * 64 + lg * 16) ^ ((r & 7) << 4)));
#pragma unroll
        for (int ni = 0; ni < 4; ++ni)
          acc[mi][ni] = __builtin_amdgcn_mfma_f32_16x16x32_bf16(afr, bfr[ni], acc[mi][ni], 0, 0, 0);
      }
    }
  }

  int sel = col0 >> 10;                 // block-uniform: 0=Q, 1=K, 2=V
  const float* bb = sel == 0 ? bq : (sel == 1 ? bk : bv);
#pragma unroll
  for (int mi = 0; mi < 4; ++mi) {
#pragma unroll
    for (int ni = 0; ni < 4; ++ni) {
#pragma unroll
      for (int q = 0; q < 4; ++q) {
        int rg = row0 + wr * 64 + mi * 16 + lg * 4 + q;
        int cg = col0 + wc * 64 + ni * 16 + lm;
        int cl = cg & 1023;
        float val = acc[mi][ni][q] + bb[cl];
        int bI = rg >> 11, s = rg & 2047;
        int nn = cl >> 8, d = cl & 255;
        if (sel == 0) {
          Qb[(size_t)rg * 1024 + cl] = f2bf(val * qscale);
        } else if (sel == 1) {
          Kg[((size_t)((nn * 8 + bI) * 32 + (d >> 3))) * 16384 + (size_t)s * 8 + (d & 7)] = f2bf(val);
        } else {
          int t2 = s >> 6, u = s & 63;
          int p = ((u >> 4) & 3) * 2 + ((u >> 2) & 1);
          int jv = ((u >> 3) & 1) * 4 + (u & 3);
          Vt[(((size_t)(nn * 8 + bI) * 32 + t2) * 2048 + p * 256 + d) * 8 + jv] = f2bf(val);
        }
      }
    }
  }
}

// ---------------- output GEMM: [16384,1024] x [256,1024]^T -> fp32 + bo ----------------
__global__ __launch_bounds__(512, 2) void k_gemmo(
    const unsigned short* __restrict__ A,
    const unsigned short* __restrict__ B,
    const float* __restrict__ bias,
    float* __restrict__ Cout)
{
  __shared__ unsigned short As[64 * 64];
  __shared__ unsigned short Bs[256 * 64];
  int tid = threadIdx.x;
  int w = tid >> 6, l = tid & 63;
  int lg = l >> 4, lm = l & 15;
  int wr = w >> 2, wc = w & 3;
  int row0 = blockIdx.y * 64;

  const f32x4 fz = {0.f, 0.f, 0.f, 0.f};
  f32x4 acc[2][4];
  for (int i = 0; i < 2; i++) for (int j = 0; j < 4; j++) acc[i][j] = fz;

  for (int t = 0; t < 16; ++t) {
    int k0 = t << 6;
    __syncthreads();
    {
      int row = tid >> 3, cirp = (tid & 7) ^ (row & 7);
      gload16(A + (size_t)(row0 + row) * 1024 + k0 + cirp * 8,
              As + (size_t)(w * 64) * 8);
    }
#pragma unroll
    for (int j = 0; j < 4; ++j) {
      int ch = j * 512 + tid;
      int row = ch >> 3, cirp = (ch & 7) ^ (row & 7);
      gload16(B + (size_t)(row) * 1024 + k0 + cirp * 8,
              Bs + (size_t)(j * 512 + w * 64) * 8);
    }
    __syncthreads();
#pragma unroll
    for (int kt = 0; kt < 2; ++kt) {
      bf16x8 bfr[4];
#pragma unroll
      for (int ni = 0; ni < 4; ++ni) {
        int r = wc * 64 + ni * 16 + lm;
        bfr[ni] = *(const bf16x8*)((const char*)Bs + r * 128 + ((kt * 64 + lg * 16) ^ ((r & 7) << 4)));
      }
#pragma unroll
      for (int mi = 0; mi < 2; ++mi) {
        int r = wr * 32 + mi * 16 + lm;
        bf16x8 afr = *(const bf16x8*)((const char*)As + r * 128 + ((kt * 64 + lg * 16) ^ ((r & 7) << 4)));
#pragma unroll
        for (int ni = 0; ni < 4; ++ni)
          acc[mi][ni] = __builtin_amdgcn_mfma_f32_16x16x32_bf16(afr, bfr[ni], acc[mi][ni], 0, 0, 0);
      }
    }
  }

#pragma unroll
  for (int mi = 0; mi < 2; ++mi)
#pragma unroll
    for (int ni = 0; ni < 4; ++ni)
#pragma unroll
      for (int q = 0; q < 4; ++q) {
        int rg = row0 + wr * 32 + mi * 16 + lg * 4 + q;
        int cg = wc * 64 + ni * 16 + lm;
        Cout[(size_t)rg * 256 + cg] = acc[mi][ni][q] + bias[cg];
      }
}

// ---------------- flash attention: pipelined producer/consumer, K issued 2 ahead ----------------
// As r23, but K-dma moved to seg2 issuing K(t+2) -> Ks[t&1]; both K and V batches get a
// full iteration in flight. Steady wait vmcnt(16) (completes K(t+1),V(t)); t=30: vmcnt(8);
// t=31: vmcnt(0). Prologue pre-stages K(0),K(1),V(0).
__global__ __launch_bounds__(512) void k_attn(
    const unsigned short* __restrict__ Qb,
    const unsigned short* __restrict__ Kg,
    const unsigned short* __restrict__ Vt,
    unsigned short* __restrict__ comb)
{
  __shared__ unsigned short Ks[2][16384];   // 2 x 32KB
  __shared__ unsigned short Vs[2][16384];   // 2 x 32KB
  __shared__ unsigned short Ps[2][8192];    // 2 x 16KB

  int i = blockIdx.x;
  int c = i & 7, j = i >> 3;
  int nbb = c + 8 * (j >> 4);
  int qt = j & 15;
  int n = nbb >> 3, b = nbb & 7;
  int q0 = qt * 128;

  int tid = threadIdx.x;
  int w = tid >> 6, l = tid & 63;
  int m = l & 31, g = l >> 5;

  const unsigned short* kbase = Kg + (size_t)(n * 8 + b) * 32 * 16384;
  const unsigned short* vbase = Vt + (size_t)(n * 8 + b) * 32 * 16384;

  // prologue: stage K(0)->Ks[0], K(1)->Ks[1], V(0)->Vs[0] (all 8 waves)
#pragma unroll
  for (int jj = 0; jj < 4; ++jj) {
    int gK = jj * 512 + tid;
    gload16(kbase + (size_t)(gK >> 6) * 16384 + (size_t)(gK & 63) * 8, Ks[0] + (size_t)gK * 8);
    gload16(kbase + (size_t)(gK >> 6) * 16384 + (size_t)(64 + (gK & 63)) * 8, Ks[1] + (size_t)gK * 8);
    gload16(vbase + (size_t)gK * 8, Vs[0] + (size_t)gK * 8);
  }
  __syncthreads();

  if (w < 4) {
    // ================= PRODUCER (qg = w) =================
    int qg = w;
    bf16x8 qf[16];
    {
      const unsigned short* qbase = Qb + (size_t)(b * 2048 + q0 + qg * 32 + m) * 1024 + n * 256 + g * 8;
#pragma unroll
      for (int ks = 0; ks < 16; ++ks)
        qf[ks] = *(const bf16x8*)(qbase + ks * 16);
    }
    float lp = 0.f;

    for (int t = 0; t < 32; ++t) {
      const unsigned short* Kc = Ks[t & 1];
      f32x16 s0, s1;
#pragma unroll
      for (int r = 0; r < 16; ++r) { s0[r] = 0.f; s1[r] = 0.f; }
      __builtin_amdgcn_s_setprio(1);
#pragma unroll
      for (int ks = 0; ks < 16; ++ks) {
        bf16x8 k0 = *(const bf16x8*)(Kc + ((2 * ks + g) * 64 + m) * 8);
        bf16x8 k1 = *(const bf16x8*)(Kc + ((2 * ks + g) * 64 + 32 + m) * 8);
        s0 = __builtin_amdgcn_mfma_f32_32x32x16_bf16(k0, qf[ks], s0, 0, 0, 0);
        s1 = __builtin_amdgcn_mfma_f32_32x32x16_bf16(k1, qf[ks], s1, 0, 0, 0);
      }
      __builtin_amdgcn_s_setprio(0);

      float p0[16], p1[16];
#pragma unroll
      for (int r = 0; r < 16; ++r) {
        p0[r] = exp2f(s0[r] - 16.0f);
        p1[r] = exp2f(s1[r] - 16.0f);
      }
      {
        float ts = 0.f;
#pragma unroll
        for (int r = 0; r < 16; ++r) ts += p0[r] + p1[r];
        lp += ts;
      }
      {
        union { unsigned u[4]; bf16x8 v; } w0, w1, w2, w3;
#pragma unroll
        for (int wd = 0; wd < 4; ++wd) {
          w0.u[wd] = cvtpk(p0[2 * wd], p0[2 * wd + 1]);
          w1.u[wd] = cvtpk(p0[8 + 2 * wd], p0[8 + 2 * wd + 1]);
          w2.u[wd] = cvtpk(p1[2 * wd], p1[2 * wd + 1]);
          w3.u[wd] = cvtpk(p1[8 + 2 * wd], p1[8 + 2 * wd + 1]);
        }
        unsigned short* Pd = Ps[t & 1];
        *(uint4*)(Pd + ((qg * 4 + 0) * 64 + l) * 8) = *(uint4*)&w0;
        *(uint4*)(Pd + ((qg * 4 + 1) * 64 + l) * 8) = *(uint4*)&w1;
        *(uint4*)(Pd + ((qg * 4 + 2) * 64 + l) * 8) = *(uint4*)&w2;
        *(uint4*)(Pd + ((qg * 4 + 3) * 64 + l) * 8) = *(uint4*)&w3;
      }
      asm volatile("s_waitcnt lgkmcnt(0)" ::: "memory");
      __builtin_amdgcn_s_barrier();            // M(t)
      __builtin_amdgcn_sched_barrier(0);
      __builtin_amdgcn_s_barrier();            // end(t)
      __builtin_amdgcn_sched_barrier(0);
    }

    float l_s = lp + __shfl_xor(lp, 32);
    *(float*)((char*)Ps[0] + (qg * 64 + l) * 4) = l_s;
    __syncthreads();     // final

  } else {
    // ================= CONSUMER (qg = w-4, full 256 d) =================
    int qg = w - 4;
    int cid = tid - 256;   // 0..255
    f32x16 ao[8];
#pragma unroll
    for (int dt = 0; dt < 8; ++dt)
#pragma unroll
      for (int r = 0; r < 16; ++r) ao[dt][r] = 0.f;
    bf16x8 pu[4];

    for (int t = 0; t < 32; ++t) {
      // seg1: PV(t-1)
      if (t > 0) {
        const unsigned short* Pp = Ps[(t - 1) & 1];
        const unsigned short* Vp = Vs[(t - 1) & 1];
#pragma unroll
        for (int jd = 0; jd < 4; ++jd)
          *(uint4*)&pu[jd] = *(const uint4*)(Pp + ((qg * 4 + jd) * 64 + l) * 8);
        __builtin_amdgcn_s_setprio(1);
#pragma unroll
        for (int dt = 0; dt < 8; ++dt) {
          int vrow = dt * 32 + m;
#pragma unroll
          for (int ks2 = 0; ks2 < 4; ++ks2) {
            bf16x8 vf = *(const bf16x8*)(Vp + ((2 * ks2 + g) * 256 + vrow) * 8);
            ao[dt] = __builtin_amdgcn_mfma_f32_32x32x16_bf16(pu[ks2], vf, ao[dt], 0, 0, 0);
          }
        }
        __builtin_amdgcn_s_setprio(0);
      }
      __builtin_amdgcn_s_barrier();            // M(t): QK(t)/PV(t-1) buffer reads done
      __builtin_amdgcn_sched_barrier(0);

      // seg2: K-dma(t+2) -> Ks[t&1] (freed by QK(t) at M); V-dma(t+1) -> Vs[(t+1)&1]
      if (t < 30) {
        unsigned short* Kd = Ks[t & 1];
#pragma unroll
        for (int jj = 0; jj < 8; ++jj) {
          int gK = jj * 256 + cid;
          gload16(kbase + (size_t)(gK >> 6) * 16384 + ((size_t)(t + 2) * 64 + (gK & 63)) * 8,
                  Kd + (size_t)gK * 8);
        }
      }
      if (t < 31) {
        unsigned short* Vd = Vs[(t + 1) & 1];
#pragma unroll
        for (int jj = 0; jj < 8; ++jj) {
          int gK = jj * 256 + cid;
          gload16(vbase + (size_t)(t + 1) * 16384 + (size_t)gK * 8, Vd + (size_t)gK * 8);
        }
      }
      if (t < 30) {
        asm volatile("s_waitcnt vmcnt(16)" ::: "memory");  // K(t+1), V(t) complete
      } else if (t == 30) {
        asm volatile("s_waitcnt vmcnt(8)" ::: "memory");   // K(31), V(30) complete
      } else {
        asm volatile("s_waitcnt vmcnt(0)" ::: "memory");   // V(31) complete
      }
      __builtin_amdgcn_s_barrier();            // end(t)
      __builtin_amdgcn_sched_barrier(0);
    }

    // final PV(31): Ps[1], Vs[1]
    {
      const unsigned short* Pp = Ps[1];
      const unsigned short* Vp = Vs[1];
#pragma unroll
      for (int jd = 0; jd < 4; ++jd)
        *(uint4*)&pu[jd] = *(const uint4*)(Pp + ((qg * 4 + jd) * 64 + l) * 8);
      __builtin_amdgcn_s_setprio(1);
#pragma unroll
      for (int dt = 0; dt < 8; ++dt) {
        int vrow = dt * 32 + m;
#pragma unroll
        for (int ks2 = 0; ks2 < 4; ++ks2) {
          bf16x8 vf = *(const bf16x8*)(Vp + ((2 * ks2 + g) * 256 + vrow) * 8);
          ao[dt] = __builtin_amdgcn_mfma_f32_32x32x16_bf16(pu[ks2], vf, ao[dt], 0, 0, 0);
        }
      }
      __builtin_amdgcn_s_setprio(0);
    }
    __syncthreads();     // final: producers' l_s visible

    float l_s = *(const float*)((const char*)Ps[0] + (qg * 64 + l) * 4);
    float rinv[16];
#pragma unroll
    for (int r = 0; r < 16; ++r) {
      float lr = __shfl(l_s, 4 * g + (r & 3) + 8 * (r >> 2));
      rinv[r] = 1.f / lr;
    }
#pragma unroll
    for (int dt = 0; dt < 8; ++dt) {
      int col = n * 256 + dt * 32 + m;
#pragma unroll
      for (int r = 0; r < 16; ++r) {
        int rowq = q0 + qg * 32 + 4 * g + (r & 3) + 8 * (r >> 2);
        comb[(size_t)(b * 2048 + rowq) * 1024 + col] = f2bf(ao[dt][r] * rinv[r]);
      }
    }
  }
}

extern "C" void kernel_launch(void* const* d_in, const int* in_sizes, int n_in,
                              void* d_out, int out_size, void* d_ws, size_t ws_size,
                              hipStream_t stream) {
  const float* x  = (const float*)d_in[0];
  const float* Wq = (const float*)d_in[1];
  const float* bq = (const float*)d_in[2];
  const float* Wk = (const float*)d_in[3];
  const float* bk = (const float*)d_in[4];
  const float* Wv = (const float*)d_in[5];
  const float* bv = (const float*)d_in[6];
  const float* Wo = (const float*)d_in[7];
  const float* bo = (const float*)d_in[8];

  const size_t MB = 1ull << 20;
  char* ws = (char*)d_ws;
  unsigned short* xb  = (unsigned short*)(ws);            // 32MB (reused as comb)
  unsigned short* Wqt = (unsigned short*)(ws + 32 * MB);  // 6MB contiguous B [3072][1024]
  unsigned short* Wot = (unsigned short*)(ws + 38 * MB);  // 0.5MB
  unsigned short* Qb  = (unsigned short*)(ws + 40 * MB);  // 32MB
  unsigned short* Kg  = (unsigned short*)(ws + 72 * MB);  // 32MB (fragment-plane layout)
  unsigned short* Vt  = (unsigned short*)(ws + 104 * MB); // 32MB (64-kv-tile granule layout)
  unsigned short* comb = xb;

  k_prep<<<5376, 256, 0, stream>>>(x, xb, Wq, Wk, Wv, Wo, Wqt, Wot);

  const float qscale = 0.0625f * 1.44269504088896f;  // 1/sqrt(256) * log2(e)
  k_gemmqkv<<<3072, 256, 0, stream>>>(xb, Wqt, bq, bk, bv, Qb, Kg, Vt, qscale);

  k_attn<<<512, 512, 0, stream>>>(Qb, Kg, Vt, comb);

  k_gemmo<<<dim3(1, 256), 512, 0, stream>>>(comb, Wot, bo, (float*)d_out);
}

// Round 25
// 293.094 us; speedup vs baseline: 1.0234x; 1.0234x over previous
//
#include <hip/hip_runtime.h>
#include <hip/hip_bf16.h>

typedef __attribute__((ext_vector_type(8))) short bf16x8;
typedef __attribute__((ext_vector_type(4))) float f32x4;
typedef __attribute__((ext_vector_type(16))) float f32x16;

#define DEVI __device__ __forceinline__

DEVI unsigned short f2bf(float f) {
  union { float f; unsigned u; } v; v.f = f;
  unsigned r = v.u + 0x7FFFu + ((v.u >> 16) & 1u);
  return (unsigned short)(r >> 16);
}

DEVI unsigned cvtpk(float lo, float hi) {
  unsigned r;
  asm("v_cvt_pk_bf16_f32 %0, %1, %2" : "=v"(r) : "v"(lo), "v"(hi));
  return r;
}

DEVI void gload16(const void* g, void* l) {
  __builtin_amdgcn_global_load_lds(
      (const __attribute__((address_space(1))) unsigned int*)g,
      (__attribute__((address_space(3))) unsigned int*)l, 16, 0, 0);
}

// -------- merged prep: bid<2048 -> x fp32->bf16 ; else 13 transpose slices --------
__global__ void k_prep(const float* __restrict__ x, unsigned short* __restrict__ xb,
                       const float* __restrict__ Wq, const float* __restrict__ Wk,
                       const float* __restrict__ Wv, const float* __restrict__ Wo,
                       unsigned short* __restrict__ Wt, unsigned short* __restrict__ Wot) {
  __shared__ float t[32][33];
  int bid = blockIdx.x;
  if (bid < 2048) {
    int i = bid * 256 + threadIdx.x;
    const int stride = 2048 * 256;
#pragma unroll
    for (int it = 0; it < 8; ++it, i += stride) {
      float4 v = ((const float4*)x)[i];
      ushort4 o;
      o.x = f2bf(v.x); o.y = f2bf(v.y); o.z = f2bf(v.z); o.w = f2bf(v.w);
      ((ushort4*)xb)[i] = o;
    }
  } else {
    int b2 = bid - 2048;
    int z = b2 >> 8, rem = b2 & 255;
    int r0 = (rem >> 3) * 32, c0 = (rem & 7) * 32;
    const float* in = z < 4 ? Wq : (z < 8 ? Wk : (z < 12 ? Wv : Wo));
    size_t ibase = (size_t)(z < 12 ? (z & 3) : 0) * 262144;
    unsigned short* out = z < 12 ? (Wt + (size_t)z * 262144) : Wot;
    int tx = threadIdx.x & 31, ty = threadIdx.x >> 5;
    for (int i = 0; i < 32; i += 8)
      t[ty + i][tx] = in[ibase + (size_t)(r0 + ty + i) * 256 + (c0 + tx)];
    __syncthreads();
    for (int i = 0; i < 32; i += 8)
      out[(size_t)(c0 + ty + i) * 1024 + (r0 + tx)] = f2bf(t[tx][ty + i]);
  }
}

// ---------------- fused QKV GEMM: [16384,1024] x [3072,1024]^T, 128x128 tiles ----------------
__global__ __launch_bounds__(256, 3) void k_gemmqkv(
    const unsigned short* __restrict__ A,
    const unsigned short* __restrict__ B,
    const float* __restrict__ bq, const float* __restrict__ bk,
    const float* __restrict__ bv,
    unsigned short* __restrict__ Qb, unsigned short* __restrict__ Kg,
    unsigned short* __restrict__ Vt, float qscale)
{
  __shared__ unsigned short As[128 * 64];
  __shared__ unsigned short Bs[128 * 64];
  int tid = threadIdx.x;
  int w = tid >> 6, l = tid & 63;
  int lg = l >> 4, lm = l & 15;
  int wr = w >> 1, wc = w & 1;
  int bid = blockIdx.x;
  int wg = (bid & 7) * 384 + (bid >> 3);
  int rowblk = wg / 24, colblk = wg % 24;
  int row0 = rowblk * 128, col0 = colblk * 128;

  const f32x4 fz = {0.f, 0.f, 0.f, 0.f};
  f32x4 acc[4][4];
  for (int i = 0; i < 4; i++) for (int j = 0; j < 4; j++) acc[i][j] = fz;

  for (int t = 0; t < 16; ++t) {
    int k0 = t << 6;
    __syncthreads();
#pragma unroll
    for (int j = 0; j < 4; ++j) {
      int ch = j * 256 + tid;
      int row = ch >> 3, cirp = (ch & 7) ^ (row & 7);
      gload16(A + (size_t)(row0 + row) * 1024 + k0 + cirp * 8,
              As + (size_t)(j * 256 + w * 64) * 8);
      gload16(B + (size_t)(col0 + row) * 1024 + k0 + cirp * 8,
              Bs + (size_t)(j * 256 + w * 64) * 8);
    }
    __syncthreads();
#pragma unroll
    for (int kt = 0; kt < 2; ++kt) {
      bf16x8 bfr[4];
#pragma unroll
      for (int ni = 0; ni < 4; ++ni) {
        int r = wc * 64 + ni * 16 + lm;
        bfr[ni] = *(const bf16x8*)((const char*)Bs + r * 128 + ((kt * 64 + lg * 16) ^ ((r & 7) << 4)));
      }
#pragma unroll
      for (int mi = 0; mi < 4; ++mi) {
        int r = wr * 64 + mi * 16 + lm;
        bf16x8 afr = *(const bf16x8*)((const char*)As + r * 128 + ((kt * 64 + lg * 16) ^ ((r & 7) << 4)));
#pragma unroll
        for (int ni = 0; ni < 4; ++ni)
          acc[mi][ni] = __builtin_amdgcn_mfma_f32_16x16x32_bf16(afr, bfr[ni], acc[mi][ni], 0, 0, 0);
      }
    }
  }

  int sel = col0 >> 10;                 // block-uniform: 0=Q, 1=K, 2=V
  const float* bb = sel == 0 ? bq : (sel == 1 ? bk : bv);
#pragma unroll
  for (int mi = 0; mi < 4; ++mi) {
#pragma unroll
    for (int ni = 0; ni < 4; ++ni) {
#pragma unroll
      for (int q = 0; q < 4; ++q) {
        int rg = row0 + wr * 64 + mi * 16 + lg * 4 + q;
        int cg = col0 + wc * 64 + ni * 16 + lm;
        int cl = cg & 1023;
        float val = acc[mi][ni][q] + bb[cl];
        int bI = rg >> 11, s = rg & 2047;
        int nn = cl >> 8, d = cl & 255;
        if (sel == 0) {
          Qb[(size_t)rg * 1024 + cl] = f2bf(val * qscale);
        } else if (sel == 1) {
          Kg[((size_t)((nn * 8 + bI) * 32 + (d >> 3))) * 16384 + (size_t)s * 8 + (d & 7)] = f2bf(val);
        } else {
          int t2 = s >> 6, u = s & 63;
          int p = ((u >> 4) & 3) * 2 + ((u >> 2) & 1);
          int jv = ((u >> 3) & 1) * 4 + (u & 3);
          Vt[(((size_t)(nn * 8 + bI) * 32 + t2) * 2048 + p * 256 + d) * 8 + jv] = f2bf(val);
        }
      }
    }
  }
}

// ---------------- output GEMM: [16384,1024] x [256,1024]^T -> fp32 + bo ----------------
__global__ __launch_bounds__(512, 2) void k_gemmo(
    const unsigned short* __restrict__ A,
    const unsigned short* __restrict__ B,
    const float* __restrict__ bias,
    float* __restrict__ Cout)
{
  __shared__ unsigned short As[64 * 64];
  __shared__ unsigned short Bs[256 * 64];
  int tid = threadIdx.x;
  int w = tid >> 6, l = tid & 63;
  int lg = l >> 4, lm = l & 15;
  int wr = w >> 2, wc = w & 3;
  int row0 = blockIdx.y * 64;

  const f32x4 fz = {0.f, 0.f, 0.f, 0.f};
  f32x4 acc[2][4];
  for (int i = 0; i < 2; i++) for (int j = 0; j < 4; j++) acc[i][j] = fz;

  for (int t = 0; t < 16; ++t) {
    int k0 = t << 6;
    __syncthreads();
    {
      int row = tid >> 3, cirp = (tid & 7) ^ (row & 7);
      gload16(A + (size_t)(row0 + row) * 1024 + k0 + cirp * 8,
              As + (size_t)(w * 64) * 8);
    }
#pragma unroll
    for (int j = 0; j < 4; ++j) {
      int ch = j * 512 + tid;
      int row = ch >> 3, cirp = (ch & 7) ^ (row & 7);
      gload16(B + (size_t)(row) * 1024 + k0 + cirp * 8,
              Bs + (size_t)(j * 512 + w * 64) * 8);
    }
    __syncthreads();
#pragma unroll
    for (int kt = 0; kt < 2; ++kt) {
      bf16x8 bfr[4];
#pragma unroll
      for (int ni = 0; ni < 4; ++ni) {
        int r = wc * 64 + ni * 16 + lm;
        bfr[ni] = *(const bf16x8*)((const char*)Bs + r * 128 + ((kt * 64 + lg * 16) ^ ((r & 7) << 4)));
      }
#pragma unroll
      for (int mi = 0; mi < 2; ++mi) {
        int r = wr * 32 + mi * 16 + lm;
        bf16x8 afr = *(const bf16x8*)((const char*)As + r * 128 + ((kt * 64 + lg * 16) ^ ((r & 7) << 4)));
#pragma unroll
        for (int ni = 0; ni < 4; ++ni)
          acc[mi][ni] = __builtin_amdgcn_mfma_f32_16x16x32_bf16(afr, bfr[ni], acc[mi][ni], 0, 0, 0);
      }
    }
  }

#pragma unroll
  for (int mi = 0; mi < 2; ++mi)
#pragma unroll
    for (int ni = 0; ni < 4; ++ni)
#pragma unroll
      for (int q = 0; q < 4; ++q) {
        int rg = row0 + wr * 32 + mi * 16 + lg * 4 + q;
        int cg = wc * 64 + ni * 16 + lm;
        Cout[(size_t)rg * 256 + cg] = acc[mi][ni][q] + bias[cg];
      }
}

// ---------------- flash attention: pipelined producer/consumer + counted vmcnt (r23) ----------------
// 8 waves, 160KB, Ks/Vs/Ps double-buffered, QK(t) || PV(t-1). Raw barriers with counted waits:
// consumers vmcnt(8) before end(t) (K-dma(t+1) complete, V-dma(t+1) in flight), vmcnt(0) at t=31;
// producers lgkmcnt(0) before M.
__global__ __launch_bounds__(512) void k_attn(
    const unsigned short* __restrict__ Qb,
    const unsigned short* __restrict__ Kg,
    const unsigned short* __restrict__ Vt,
    unsigned short* __restrict__ comb)
{
  __shared__ unsigned short Ks[2][16384];   // 2 x 32KB
  __shared__ unsigned short Vs[2][16384];   // 2 x 32KB
  __shared__ unsigned short Ps[2][8192];    // 2 x 16KB

  int i = blockIdx.x;
  int c = i & 7, j = i >> 3;
  int nbb = c + 8 * (j >> 4);
  int qt = j & 15;
  int n = nbb >> 3, b = nbb & 7;
  int q0 = qt * 128;

  int tid = threadIdx.x;
  int w = tid >> 6, l = tid & 63;
  int m = l & 31, g = l >> 5;

  const unsigned short* kbase = Kg + (size_t)(n * 8 + b) * 32 * 16384;
  const unsigned short* vbase = Vt + (size_t)(n * 8 + b) * 32 * 16384;

  // prologue: all 8 waves stage K(0)->Ks[0], V(0)->Vs[0]
#pragma unroll
  for (int jj = 0; jj < 4; ++jj) {
    int gK = jj * 512 + tid;
    gload16(kbase + (size_t)(gK >> 6) * 16384 + (size_t)(gK & 63) * 8, Ks[0] + (size_t)gK * 8);
    gload16(vbase + (size_t)gK * 8, Vs[0] + (size_t)gK * 8);
  }
  __syncthreads();

  if (w < 4) {
    // ================= PRODUCER (qg = w) =================
    int qg = w;
    bf16x8 qf[16];
    {
      const unsigned short* qbase = Qb + (size_t)(b * 2048 + q0 + qg * 32 + m) * 1024 + n * 256 + g * 8;
#pragma unroll
      for (int ks = 0; ks < 16; ++ks)
        qf[ks] = *(const bf16x8*)(qbase + ks * 16);
    }
    float lp = 0.f;

    for (int t = 0; t < 32; ++t) {
      const unsigned short* Kc = Ks[t & 1];
      f32x16 s0, s1;
#pragma unroll
      for (int r = 0; r < 16; ++r) { s0[r] = 0.f; s1[r] = 0.f; }
      __builtin_amdgcn_s_setprio(1);
#pragma unroll
      for (int ks = 0; ks < 16; ++ks) {
        bf16x8 k0 = *(const bf16x8*)(Kc + ((2 * ks + g) * 64 + m) * 8);
        bf16x8 k1 = *(const bf16x8*)(Kc + ((2 * ks + g) * 64 + 32 + m) * 8);
        s0 = __builtin_amdgcn_mfma_f32_32x32x16_bf16(k0, qf[ks], s0, 0, 0, 0);
        s1 = __builtin_amdgcn_mfma_f32_32x32x16_bf16(k1, qf[ks], s1, 0, 0, 0);
      }
      __builtin_amdgcn_s_setprio(0);

      float p0[16], p1[16];
#pragma unroll
      for (int r = 0; r < 16; ++r) {
        p0[r] = exp2f(s0[r] - 16.0f);
        p1[r] = exp2f(s1[r] - 16.0f);
      }
      {
        float ts = 0.f;
#pragma unroll
        for (int r = 0; r < 16; ++r) ts += p0[r] + p1[r];
        lp += ts;
      }
      {
        union { unsigned u[4]; bf16x8 v; } w0, w1, w2, w3;
#pragma unroll
        for (int wd = 0; wd < 4; ++wd) {
          w0.u[wd] = cvtpk(p0[2 * wd], p0[2 * wd + 1]);
          w1.u[wd] = cvtpk(p0[8 + 2 * wd], p0[8 + 2 * wd + 1]);
          w2.u[wd] = cvtpk(p1[2 * wd], p1[2 * wd + 1]);
          w3.u[wd] = cvtpk(p1[8 + 2 * wd], p1[8 + 2 * wd + 1]);
        }
        unsigned short* Pd = Ps[t & 1];
        *(uint4*)(Pd + ((qg * 4 + 0) * 64 + l) * 8) = *(uint4*)&w0;
        *(uint4*)(Pd + ((qg * 4 + 1) * 64 + l) * 8) = *(uint4*)&w1;
        *(uint4*)(Pd + ((qg * 4 + 2) * 64 + l) * 8) = *(uint4*)&w2;
        *(uint4*)(Pd + ((qg * 4 + 3) * 64 + l) * 8) = *(uint4*)&w3;
      }
      asm volatile("s_waitcnt lgkmcnt(0)" ::: "memory");
      __builtin_amdgcn_s_barrier();            // M(t)
      __builtin_amdgcn_sched_barrier(0);
      __builtin_amdgcn_s_barrier();            // end(t)
      __builtin_amdgcn_sched_barrier(0);
    }

    float l_s = lp + __shfl_xor(lp, 32);
    *(float*)((char*)Ps[0] + (qg * 64 + l) * 4) = l_s;
    __syncthreads();     // final

  } else {
    // ================= CONSUMER (qg = w-4, full 256 d) =================
    int qg = w - 4;
    int cid = tid - 256;   // 0..255
    f32x16 ao[8];
#pragma unroll
    for (int dt = 0; dt < 8; ++dt)
#pragma unroll
      for (int r = 0; r < 16; ++r) ao[dt][r] = 0.f;
    bf16x8 pu[4];

    for (int t = 0; t < 32; ++t) {
      // K-dma(t+1) -> Ks[(t+1)&1]
      if (t < 31) {
        unsigned short* Kd = Ks[(t + 1) & 1];
#pragma unroll
        for (int jj = 0; jj < 8; ++jj) {
          int gK = jj * 256 + cid;
          gload16(kbase + (size_t)(gK >> 6) * 16384 + ((size_t)(t + 1) * 64 + (gK & 63)) * 8,
                  Kd + (size_t)gK * 8);
        }
      }
      // PV(t-1)
      if (t > 0) {
        const unsigned short* Pp = Ps[(t - 1) & 1];
        const unsigned short* Vp = Vs[(t - 1) & 1];
#pragma unroll
        for (int jd = 0; jd < 4; ++jd)
          *(uint4*)&pu[jd] = *(const uint4*)(Pp + ((qg * 4 + jd) * 64 + l) * 8);
        __builtin_amdgcn_s_setprio(1);
#pragma unroll
        for (int dt = 0; dt < 8; ++dt) {
          int vrow = dt * 32 + m;
#pragma unroll
          for (int ks2 = 0; ks2 < 4; ++ks2) {
            bf16x8 vf = *(const bf16x8*)(Vp + ((2 * ks2 + g) * 256 + vrow) * 8);
            ao[dt] = __builtin_amdgcn_mfma_f32_32x32x16_bf16(pu[ks2], vf, ao[dt], 0, 0, 0);
          }
        }
        __builtin_amdgcn_s_setprio(0);
      }
      __builtin_amdgcn_s_barrier();            // M(t): PV reads of Vs[(t-1)&1] done
      __builtin_amdgcn_sched_barrier(0);

      // V-dma(t+1) -> Vs[(t+1)&1] (same parity buffer PV(t-1) just released)
      if (t < 31) {
        unsigned short* Vd = Vs[(t + 1) & 1];
#pragma unroll
        for (int jj = 0; jj < 8; ++jj) {
          int gK = jj * 256 + cid;
          gload16(vbase + (size_t)(t + 1) * 16384 + (size_t)gK * 8, Vd + (size_t)gK * 8);
        }
        asm volatile("s_waitcnt vmcnt(8)" ::: "memory");  // K-dma(t+1) + all older done
      } else {
        asm volatile("s_waitcnt vmcnt(0)" ::: "memory");  // V-dma(31) done for final PV
      }
      __builtin_amdgcn_s_barrier();            // end(t)
      __builtin_amdgcn_sched_barrier(0);
    }

    // final PV(31): Ps[1], Vs[1]
    {
      const unsigned short* Pp = Ps[1];
      const unsigned short* Vp = Vs[1];
#pragma unroll
      for (int jd = 0; jd < 4; ++jd)
        *(uint4*)&pu[jd] = *(const uint4*)(Pp + ((qg * 4 + jd) * 64 + l) * 8);
      __builtin_amdgcn_s_setprio(1);
#pragma unroll
      for (int dt = 0; dt < 8; ++dt) {
        int vrow = dt * 32 + m;
#pragma unroll
        for (int ks2 = 0; ks2 < 4; ++ks2) {
          bf16x8 vf = *(const bf16x8*)(Vp + ((2 * ks2 + g) * 256 + vrow) * 8);
          ao[dt] = __builtin_amdgcn_mfma_f32_32x32x16_bf16(pu[ks2], vf, ao[dt], 0, 0, 0);
        }
      }
      __builtin_amdgcn_s_setprio(0);
    }
    __syncthreads();     // final: producers' l_s visible

    float l_s = *(const float*)((const char*)Ps[0] + (qg * 64 + l) * 4);
    float rinv[16];
#pragma unroll
    for (int r = 0; r < 16; ++r) {
      float lr = __shfl(l_s, 4 * g + (r & 3) + 8 * (r >> 2));
      rinv[r] = 1.f / lr;
    }
#pragma unroll
    for (int dt = 0; dt < 8; ++dt) {
      int col = n * 256 + dt * 32 + m;
#pragma unroll
      for (int r = 0; r < 16; ++r) {
        int rowq = q0 + qg * 32 + 4 * g + (r & 3) + 8 * (r >> 2);
        comb[(size_t)(b * 2048 + rowq) * 1024 + col] = f2bf(ao[dt][r] * rinv[r]);
      }
    }
  }
}

extern "C" void kernel_launch(void* const* d_in, const int* in_sizes, int n_in,
                              void* d_out, int out_size, void* d_ws, size_t ws_size,
                              hipStream_t stream) {
  const float* x  = (const float*)d_in[0];
  const float* Wq = (const float*)d_in[1];
  const float* bq = (const float*)d_in[2];
  const float* Wk = (const float*)d_in[3];
  const float* bk = (const float*)d_in[4];
  const float* Wv = (const float*)d_in[5];
  const float* bv = (const float*)d_in[6];
  const float* Wo = (const float*)d_in[7];
  const float* bo = (const float*)d_in[8];

  const size_t MB = 1ull << 20;
  char* ws = (char*)d_ws;
  unsigned short* xb  = (unsigned short*)(ws);            // 32MB (reused as comb)
  unsigned short* Wqt = (unsigned short*)(ws + 32 * MB);  // 6MB contiguous B [3072][1024]
  unsigned short* Wot = (unsigned short*)(ws + 38 * MB);  // 0.5MB
  unsigned short* Qb  = (unsigned short*)(ws + 40 * MB);  // 32MB
  unsigned short* Kg  = (unsigned short*)(ws + 72 * MB);  // 32MB (fragment-plane layout)
  unsigned short* Vt  = (unsigned short*)(ws + 104 * MB); // 32MB (64-kv-tile granule layout)
  unsigned short* comb = xb;

  k_prep<<<5376, 256, 0, stream>>>(x, xb, Wq, Wk, Wv, Wo, Wqt, Wot);

  const float qscale = 0.0625f * 1.44269504088896f;  // 1/sqrt(256) * log2(e)
  k_gemmqkv<<<3072, 256, 0, stream>>>(xb, Wqt, bq, bk, bv, Qb, Kg, Vt, qscale);

  k_attn<<<512, 512, 0, stream>>>(Qb, Kg, Vt, comb);

  k_gemmo<<<dim3(1, 256), 512, 0, stream>>>(comb, Wot, bo, (float*)d_out);
}